// Round 6
// baseline (260.009 us; speedup 1.0000x reference)
//
#include <hip/hip_runtime.h>

// Cost volume: volume[b,d,h,w] = mean_c left[b,c,h,w] * right[b,c,h,w-d], 0 for w<d.
// B=8 C=64 H=160 W=320 D=48, f32 in / f32 out.
//
// Grid 2560 = (b,h,half): each 128-thread block does one half-row (160 w's).
// Channels streamed in 8 chunks of 8, double-buffered LDS 24 KB -> 6 blocks/CU
// (12 waves/CU), ~10 blocks/CU queued: six independent pipelines per CU.
// Per chunk: L [8][160], R [8][224] (w-halo of 64 so all compute reads land
// in-buffer; left-half negative-w global loads clamp to row start and only
// feed store-masked outputs). Each wave issues exactly 6 x 1KB
// global_load_lds per chunk -> counted s_waitcnt vmcnt(6), never 0 in loop.
// Thread t (t<120) owns w-quad w0=(t%40)*4 (16B lane stride, conflict-free
// ds_read_b128) x 16-deep d-tile d0=(t/40)*16. 1.5 LDS bytes per FMA.

constexpr int C_ = 64, H_ = 160, W_ = 320, D_ = 48;
constexpr int HW_ = H_ * W_;            // 51200
constexpr int CK_  = 8;                 // channels per chunk
constexpr int WH_  = 160;               // half-row width
constexpr int RW_  = 224;               // staged R row = WH_ + 64 halo
constexpr int LFL  = CK_ * WH_;         // 1280 floats (5 x 1KB segs)
constexpr int RFL  = CK_ * RW_;         // 1792 floats (7 x 1KB segs)
constexpr int BUF  = LFL + RFL;         // 3072 floats per buffer

typedef __attribute__((address_space(1))) unsigned int gu32;
typedef __attribute__((address_space(3))) unsigned int lu32;
typedef float f32x4 __attribute__((ext_vector_type(4)));

__device__ __forceinline__ void gload_lds16(const float* g, float* l) {
  __builtin_amdgcn_global_load_lds((const gu32*)g, (lu32*)l, 16, 0, 0);
}

__global__ __launch_bounds__(128, 2)
void corvol_kernel(const float* __restrict__ L, const float* __restrict__ R,
                   float* __restrict__ out) {
  __shared__ __align__(16) float lds[2 * BUF];   // 24576 B

  const int tid  = threadIdx.x;
  const int lane = tid & 63;
  const int wv   = tid >> 6;              // 0..1

  const int bid  = blockIdx.x;
  const int half = bid & 1;
  const int bh   = bid >> 1;              // b*H + h
  const int b    = bh / H_;
  const int h    = bh - b * H_;
  const int inbase = b * (C_ * HW_) + h * W_;

  // 12 staging segments of 1KB per chunk: segs 0..4 = L rows, 5..11 = R rows.
  // wave0 -> segs 0..5, wave1 -> segs 6..11 (6 loads per wave per chunk).
  const float* gsrc[6];
  int ldst[6];
#pragma unroll
  for (int s = 0; s < 6; ++s) {
    const int seg = wv * 6 + s;
    if (seg < 5) {                        // L segment
      const int f = seg * 256 + lane * 4; // float idx in [8][160] (16B within row)
      const int c = f / WH_;
      const int o = f - c * WH_;
      gsrc[s] = L + inbase + c * HW_ + half * WH_ + o;
      ldst[s] = seg * 256;
    } else {                              // R segment
      const int t = seg - 5;
      const int f = t * 256 + lane * 4;   // float idx in [8][224]
      const int c = f / RW_;
      const int wr = f - c * RW_;
      int base = half * WH_ - 64 + wr;    // may be negative only for half==0
      if (base < 0) base = 0;             // clamp: garbage feeds masked outputs only
      gsrc[s] = R + inbase + c * HW_ + base;
      ldst[s] = LFL + t * 256;
    }
  }

  // thread -> (d-tile, w-quad): 40 quads x 3 d-tiles = 120 active of 128
  const int q  = tid % 40;
  const int dt = tid / 40;
  const int w0 = q * 4;
  const int d0 = dt * 16;
  const bool active = (dt < 3);

  float acc[16][4];
#pragma unroll
  for (int i = 0; i < 16; ++i)
#pragma unroll
    for (int j = 0; j < 4; ++j) acc[i][j] = 0.0f;

  auto stage = [&](int ck, int p) {
    const int cb = ck * CK_ * HW_;
    float* lb = &lds[p * BUF];
#pragma unroll
    for (int s = 0; s < 6; ++s)
      gload_lds16(gsrc[s] + cb, lb + ldst[s]);
  };

  auto compute = [&](int p) {
    const float* Lc = &lds[p * BUF];
    const float* Rc = &lds[p * BUF + LFL];
#pragma unroll
    for (int c = 0; c < CK_; ++c) {
      const f32x4 a = *(const f32x4*)(Lc + c * WH_ + w0);
      // R local l corresponds to global w = half*WH_ - 64 + l.
      // FMA(dd,j) needs l = w0 + j - (d0+dd) + 64 = base + (16 + j - dd),
      // base = w0 - d0 + 48 in [16, 204], reads rv[1..19] -> l in [17,223]. In-buffer.
      const float* rp = Rc + c * RW_ + (w0 - d0 + 48);
      float rv[20];
#pragma unroll
      for (int k = 0; k < 5; ++k) {
        const f32x4 r = *(const f32x4*)(rp + 4 * k);
        rv[4 * k + 0] = r.x; rv[4 * k + 1] = r.y;
        rv[4 * k + 2] = r.z; rv[4 * k + 3] = r.w;
      }
      const float la[4] = {a.x, a.y, a.z, a.w};
#pragma unroll
      for (int dd = 0; dd < 16; ++dd)
#pragma unroll
        for (int j = 0; j < 4; ++j)
          acc[dd][j] = fmaf(la[j], rv[16 + j - dd], acc[dd][j]);
    }
  };

  stage(0, 0);                            // 6 loads in flight per wave

#pragma unroll 1
  for (int ck = 0; ck < 8; ++ck) {
    if (ck < 7) stage(ck + 1, (ck + 1) & 1);      // +6 loads (12 in flight)
    if (ck < 7) asm volatile("s_waitcnt vmcnt(6)" ::: "memory");
    else        asm volatile("s_waitcnt vmcnt(0)" ::: "memory");
    __builtin_amdgcn_sched_barrier(0);
    __builtin_amdgcn_s_barrier();                 // chunk ck fully in LDS
    __builtin_amdgcn_sched_barrier(0);
    if (active) compute(ck & 1);
    if (ck < 7) {
      __builtin_amdgcn_sched_barrier(0);
      __builtin_amdgcn_s_barrier();               // WAR: buffer free for stage(ck+2)
      __builtin_amdgcn_sched_barrier(0);
    }
  }

  if (active) {
    constexpr float sc = 1.0f / 64.0f;
    const int wg = half * WH_ + w0;       // global w of this quad
    const int ob = b * (D_ * HW_) + h * W_ + wg;
#pragma unroll
    for (int dd = 0; dd < 16; ++dd) {
      const int d = d0 + dd;
      f32x4 o;
      o.x = (wg + 0 >= d) ? acc[dd][0] * sc : 0.0f;
      o.y = (wg + 1 >= d) ? acc[dd][1] * sc : 0.0f;
      o.z = (wg + 2 >= d) ? acc[dd][2] * sc : 0.0f;
      o.w = (wg + 3 >= d) ? acc[dd][3] * sc : 0.0f;
      __builtin_nontemporal_store(o, (f32x4*)(out + ob + d * HW_));
    }
  }
}

extern "C" void kernel_launch(void* const* d_in, const int* in_sizes, int n_in,
                              void* d_out, int out_size, void* d_ws, size_t ws_size,
                              hipStream_t stream) {
  const float* left  = (const float*)d_in[0];
  const float* right = (const float*)d_in[1];
  float* out = (float*)d_out;
  const int B = 8;
  dim3 grid(B * H_ * 2), block(128);
  corvol_kernel<<<grid, block, 0, stream>>>(left, right, out);
}